// Round 10
// baseline (283.526 us; speedup 1.0000x reference)
//
#include <hip/hip_runtime.h>
#include <hip/hip_bf16.h>

typedef unsigned short u16;
typedef unsigned int u32;
typedef __attribute__((ext_vector_type(8))) short bf16x8;
typedef __attribute__((ext_vector_type(4))) float f32x4;

#define T_STEPS 64
#define BN_TOT  8192
#define BM      32

// workspace byte offsets
#define OFF_WHH0  0u
#define OFF_WIH0  131072u
#define OFF_W1    163840u
#define OFF_B0    425984u
#define OFF_B1    428032u
#define OFF_WEFF  430080u
#define OFF_BEFF  432128u
#define OFF_XB    432192u

// LDS: whh0 frags (128KB) + hA + hB0 + hB1 (8KB each, col-block-major)
#define HB        8192
#define LDS_BYTES (131072 + 3*HB)   // 155648

__device__ __forceinline__ u16 f2bu(float f) {
  unsigned u = __float_as_uint(f);
  unsigned r = (u + 0x7FFFu + ((u >> 16) & 1u)) >> 16;
  return (u16)r;
}
__device__ __forceinline__ float bu2f(u16 u) {
  return __uint_as_float(((unsigned)u) << 16);
}
__device__ __forceinline__ float fsig(float x) {
  return __builtin_amdgcn_rcpf(1.0f + __builtin_amdgcn_exp2f(-1.44269504f * x));
}
__device__ __forceinline__ unsigned cvt_pk_bf16(float lo, float hi) {
  unsigned r;
  asm("v_cvt_pk_bf16_f32 %0, %1, %2" : "=v"(r) : "v"(lo), "v"(hi));
  return r;
}
__device__ __forceinline__ f32x4 mfma16(bf16x8 a, bf16x8 b, f32x4 c) {
  return __builtin_amdgcn_mfma_f32_16x16x32_bf16(a, b, c, 0, 0, 0);
}

union U16x8 { u16 u[8]; uint4 q; };

// ---------------- prep: weights -> fragment-ordered bf16, collapsed head ----
__global__ void lstm_prep_w(const float* Wih0, const float* Whh0,
                            const float* bih0, const float* bhh0,
                            const float* Wih1, const float* Whh1,
                            const float* bih1, const float* bhh1,
                            const float* muW1, const float* mub1,
                            const float* muW2, const float* mub2,
                            const float* sgW1, const float* sgb1,
                            const float* sgW2, const float* sgb2,
                            unsigned char* ws)
{
  int id = blockIdx.x * 256 + threadIdx.x;
  u16* whh0_f = (u16*)(ws + OFF_WHH0);
  u16* wih0_f = (u16*)(ws + OFF_WIH0);
  u16* w1_f   = (u16*)(ws + OFF_W1);
  float* b0   = (float*)(ws + OFF_B0);
  float* b1   = (float*)(ws + OFF_B1);
  float* weff = (float*)(ws + OFF_WEFF);
  float* beff = (float*)(ws + OFF_BEFF);

  if (id < 8192) {                       // Whh0 frags: [w][g][kf][lane][8]
    int fid = id >> 6, lane = id & 63;
    int w = fid >> 4, g = (fid >> 2) & 3, kf = fid & 3;
    int r = g*128 + w*16 + (lane & 15);
    int k = kf*32 + (lane >> 4)*8;
    const float* src = Whh0 + r*128 + k;
    U16x8 t;
    #pragma unroll
    for (int i = 0; i < 8; ++i) t.u[i] = f2bu(src[i]);
    ((uint4*)whh0_f)[id] = t.q;
  } else if (id < 10240) {               // Wih0 frags (K=8 in 32, zero-padded)
    int c = id - 8192; int fid = c >> 6, lane = c & 63;
    int w = fid >> 2, g = fid & 3;
    U16x8 t;
    #pragma unroll
    for (int i = 0; i < 8; ++i) t.u[i] = 0;
    if (lane < 16) {
      int r = g*128 + w*16 + lane;
      #pragma unroll
      for (int i = 0; i < 8; ++i) t.u[i] = f2bu(Wih0[r*8 + i]);
    }
    ((uint4*)wih0_f)[c] = t.q;
  } else if (id < 26624) {               // W1 = [Wih1 ; Whh1] frags, K=256
    int c = id - 10240; int fid = c >> 6, lane = c & 63;
    int w = fid >> 5, g = (fid >> 3) & 3, kf = fid & 7;
    int r = g*128 + w*16 + (lane & 15);
    int k = kf*32 + (lane >> 4)*8;
    const float* src = (k < 128) ? (Wih1 + r*128 + k) : (Whh1 + r*128 + (k-128));
    U16x8 t;
    #pragma unroll
    for (int i = 0; i < 8; ++i) t.u[i] = f2bu(src[i]);
    ((uint4*)w1_f)[c] = t.q;
  } else if (id < 27136) {               // b0 arranged
    int i = id - 26624; int w = i >> 6, g = (i >> 4) & 3, cc = i & 15;
    int r = g*128 + w*16 + cc;
    b0[i] = bih0[r] + bhh0[r];
  } else if (id < 27648) {               // b1 arranged
    int i = id - 27136; int w = i >> 6, g = (i >> 4) & 3, cc = i & 15;
    int r = g*128 + w*16 + cc;
    b1[i] = bih1[r] + bhh1[r];
  } else if (id < 28160) {               // collapsed head W: [4][128]
    int i = id - 27648; int o = i >> 7, k = i & 127;
    const float* W1p = (o < 2) ? muW1 : sgW1;
    const float* W2p = (o < 2) ? muW2 : sgW2;
    int oo = o & 1;
    float s = 0.f;
    for (int m = 0; m < 64; ++m) s += W2p[oo*64 + m] * W1p[m*128 + k];
    weff[i] = s;
  } else if (id < 28164) {               // collapsed head bias [4]
    int o = id - 28160; int oo = o & 1;
    const float* W2p = (o < 2) ? muW2 : sgW2;
    const float* b1p = (o < 2) ? mub1 : sgb1;
    const float* b2p = (o < 2) ? mub2 : sgb2;
    float s = b2p[oo];
    for (int m = 0; m < 64; ++m) s += W2p[oo*64 + m] * b1p[m];
    beff[o] = s;
  }
}

// ---------------- prep: in_tensor [B,T,N,D] fp32 -> xb [T, BN, 8] bf16 ------
__global__ void lstm_prep_x(const float* in, unsigned char* ws)
{
  int id = blockIdx.x * 256 + threadIdx.x;     // < 524288
  if (id >= T_STEPS * BN_TOT) return;
  int t = id >> 13, s = id & 8191, b = s >> 9, n = s & 511;
  const float* src = in + (((b*64) + t)*512 + n)*8;
  U16x8 v;
  #pragma unroll
  for (int i = 0; i < 8; ++i) v.u[i] = f2bu(src[i]);
  *(uint4*)(ws + OFF_XB + (size_t)id * 16) = v.q;
}

// ---------------- main: fused 2-layer LSTM + head ---------------------------
// R10 = R9 (best: 270us) + three VALU-issue cuts:
// 1) ACT: shared-denominator exp form. Exact algebra:
//      c = [c_prev*a1*a3 + (1-eg)*a2] * rcp(a1*a2*a3),  a_i = 1+exp(-gate)
//      h = (1-ec) * rcp((1+eo)*(1+ec)),                 ec  = exp(-2*clamp(c))
//    5 exp + 2 rcp per cell (was 5+5); leading exps are independent.
// 2) bias-as-C: first MFMA of each acc takes the pre-splatted bias as C
//    (D != C legal) -> no 64x v_mov acc-init per step.
// 3) 2 barriers/step: bar3 removed; ACT1(t)->L1m(t+1) RAW crosses
//    bar1(t+1)+bar2(t+1); hbR WAR blocked by bar1 (verified per-hazard).
// h layout: col-block-major, addr(row,col) = (col>>3)*512 + row*16 + (col&7)*2
#define ACT_BLOCK(ACC, CS, HBASE)                                          \
  { _Pragma("unroll")                                                      \
    for (int mf = 0; mf < 2; ++mf) {                                       \
      float hq[4];                                                         \
      _Pragma("unroll")                                                    \
      for (int q = 0; q < 4; ++q) {                                        \
        float ei = __builtin_amdgcn_exp2f(-1.44269504f * ACC[mf][0][q]);   \
        float ef = __builtin_amdgcn_exp2f(-1.44269504f * ACC[mf][1][q]);   \
        float eg = __builtin_amdgcn_exp2f(-2.88539008f * ACC[mf][2][q]);   \
        float eo = __builtin_amdgcn_exp2f(-1.44269504f * ACC[mf][3][q]);   \
        float a1 = 1.0f + ei, a2 = 1.0f + ef, a3 = 1.0f + eg;              \
        float p13 = a1 * a3;                                               \
        float num = fmaf(CS[mf][q], p13, (1.0f - eg) * a2);                \
        float c = num * __builtin_amdgcn_rcpf(p13 * a2);                   \
        CS[mf][q] = c;                                                     \
        float cc = fminf(fmaxf(c, -40.0f), 40.0f);                         \
        float ec = __builtin_amdgcn_exp2f(-2.88539008f * cc);              \
        hq[q] = (1.0f - ec) * __builtin_amdgcn_rcpf((1.0f + eo) * (1.0f + ec)); \
      }                                                                    \
      unsigned p01 = cvt_pk_bf16(hq[0], hq[1]);                            \
      unsigned p23 = cvt_pk_bf16(hq[2], hq[3]);                            \
      int rb = (mf*16 + lk*4);                                             \
      *(u16*)((HBASE) + wb + (rb  )*16) = (u16)p01;                        \
      *(u16*)((HBASE) + wb + (rb+1)*16) = (u16)(p01 >> 16);                \
      *(u16*)((HBASE) + wb + (rb+2)*16) = (u16)p23;                        \
      *(u16*)((HBASE) + wb + (rb+3)*16) = (u16)(p23 >> 16);                \
    } }

__global__ __launch_bounds__(512, 2) void lstm_fused(const unsigned char* ws, float* out)
{
  extern __shared__ unsigned char lds[];
  u16* whh0_lds = (u16*)lds;                 // [w][g][kf][lane][8] frags, 128KB
  unsigned char* hA  = lds + 131072;
  unsigned char* hB0 = hA + HB;
  unsigned char* hB1 = hB0 + HB;

  const u16* whh0_f = (const u16*)(ws + OFF_WHH0);
  const u16* wih0_f = (const u16*)(ws + OFF_WIH0);
  const u16* w1_f   = (const u16*)(ws + OFF_W1);
  const float* b0a  = (const float*)(ws + OFF_B0);
  const float* b1a  = (const float*)(ws + OFF_B1);
  const float* weff = (const float*)(ws + OFF_WEFF);
  const float* beff = (const float*)(ws + OFF_BEFF);
  const u16* xb     = (const u16*)(ws + OFF_XB);

  const int tid = threadIdx.x;
  const int w = tid >> 6, l = tid & 63;
  const int lrow = l & 15, lk = l >> 4;
  const int s0 = blockIdx.x * BM;
  const int wb = (w*2 + (lrow >> 3))*512 + (lrow & 7)*2;   // ACT write base

  // stage Whh0 frags into LDS (straight 16B copies, layout identical)
  for (int i = tid; i < 8192; i += 512)
    ((uint4*)whh0_lds)[i] = ((const uint4*)whh0_f)[i];
  // zero all three h buffers (contiguous 24KB)
  for (int i = tid; i < 6144; i += 512) ((u32*)hA)[i] = 0;

  // persistent register weights (plain arrays, builtin consumers: compiler
  // promotes w1r to AGPRs itself -- R2/R9 evidence)
  bf16x8 w1r[4][8];
  #pragma unroll
  for (int g = 0; g < 4; ++g)
    #pragma unroll
    for (int kf = 0; kf < 8; ++kf)
      w1r[g][kf] = *(const bf16x8*)(w1_f + ((((w*4+g)*8)+kf)*64 + l)*8);
  bf16x8 wih0r[4];
  #pragma unroll
  for (int g = 0; g < 4; ++g)
    wih0r[g] = *(const bf16x8*)(wih0_f + ((w*4+g)*64 + l)*8);
  // bias splats, used as the C operand of the FIRST MFMA of each acc chain
  f32x4 biasC0[4], biasC1[4];
  #pragma unroll
  for (int g = 0; g < 4; ++g) {
    float b0s = b0a[w*64 + g*16 + lrow];
    float b1s = b1a[w*64 + g*16 + lrow];
    biasC0[g] = (f32x4){b0s, b0s, b0s, b0s};
    biasC1[g] = (f32x4){b1s, b1s, b1s, b1s};
  }
  float c_a[2][4] = {{0,0,0,0},{0,0,0,0}};
  float c_b[2][4] = {{0,0,0,0},{0,0,0,0}};

  unsigned char* hbR = hB0;   // layer-1 h_prev (zero at t=0)
  unsigned char* hbW = hB1;

  // x software pipeline: xf holds step t's fragment; loaded one phase early
  bf16x8 xf0 = {0,0,0,0,0,0,0,0}, xf1 = {0,0,0,0,0,0,0,0};
  if (lk == 0) {
    xf0 = *(const bf16x8*)(xb + (size_t)(s0 + lrow)*8);
    xf1 = *(const bf16x8*)(xb + (size_t)(s0 + 16 + lrow)*8);
  }
  __syncthreads();

  #pragma unroll 1
  for (int t = 0; t < T_STEPS; ++t) {
    // ---- seg1: L0m(t) = bias + x@Wih0^T + hA@Whh0^T ------------------------
    f32x4 acc[2][4];
    #pragma unroll
    for (int g = 0; g < 4; ++g) {
      acc[0][g] = mfma16(xf0, wih0r[g], biasC0[g]);   // bias as C operand
      acc[1][g] = mfma16(xf1, wih0r[g], biasC0[g]);
    }
    // prefetch next step's x (L2 latency hides under the rest of the step)
    if (t + 1 < T_STEPS && lk == 0) {
      xf0 = *(const bf16x8*)(xb + (size_t)((t+1)*8192 + s0 + lrow)*8);
      xf1 = *(const bf16x8*)(xb + (size_t)((t+1)*8192 + s0 + 16 + lrow)*8);
    }
    #pragma unroll
    for (int kf = 0; kf < 4; ++kf) {
      bf16x8 a0 = *(const bf16x8*)(hA + (kf*4 + lk)*512 + lrow*16);
      bf16x8 a1 = *(const bf16x8*)(hA + (kf*4 + lk)*512 + (16 + lrow)*16);
      #pragma unroll
      for (int g = 0; g < 4; ++g) {
        bf16x8 bfr = *(const bf16x8*)(whh0_lds + ((w*16 + g*4 + kf)*64 + l)*8);
        acc[0][g] = mfma16(a0, bfr, acc[0][g]);
        acc[1][g] = mfma16(a1, bfr, acc[1][g]);
      }
    }
    __syncthreads();                       // bar1: hA reads + prior hB writes done
    // ---- seg2: ACT0(t) -> hA(t) -------------------------------------------
    ACT_BLOCK(acc, c_a, hA);
    __syncthreads();                       // bar2: hA(t) visible

    // ---- seg3: L1m(t) = bias + hA@Wih1^T + hbR@Whh1^T, then ACT1(t) -------
    {
      bf16x8 a0 = *(const bf16x8*)(hA + lk*512 + lrow*16);
      bf16x8 a1 = *(const bf16x8*)(hA + lk*512 + (16 + lrow)*16);
      #pragma unroll
      for (int g = 0; g < 4; ++g) {
        acc[0][g] = mfma16(a0, w1r[g][0], biasC1[g]);  // kf=0 carries the bias
        acc[1][g] = mfma16(a1, w1r[g][0], biasC1[g]);
      }
    }
    #pragma unroll
    for (int kf = 1; kf < 8; ++kf) {
      const unsigned char* hs = (kf < 4) ? hA : hbR;
      bf16x8 a0 = *(const bf16x8*)(hs + ((kf & 3)*4 + lk)*512 + lrow*16);
      bf16x8 a1 = *(const bf16x8*)(hs + ((kf & 3)*4 + lk)*512 + (16 + lrow)*16);
      #pragma unroll
      for (int g = 0; g < 4; ++g) {
        acc[0][g] = mfma16(a0, w1r[g][kf], acc[0][g]);
        acc[1][g] = mfma16(a1, w1r[g][kf], acc[1][g]);
      }
    }
    // ACT1 writes hbW (ping-pong): RAW to L1m(t+1) crosses bar1+bar2 of t+1;
    // WAR on hbR blocked by bar1(t+1). No barrier here.
    ACT_BLOCK(acc, c_b, hbW);
    { unsigned char* tp = hbR; hbR = hbW; hbW = tp; }
  }
  __syncthreads();                         // final hB visible for the head

  // ---- head: out = sigmoid(h_final @ Weff^T + beff), sigma *= 0.5 ----------
  if (tid < BM*4) {
    int m = tid >> 2, o = tid & 3;
    const float* wr = weff + o*128;
    float d = beff[o];
    #pragma unroll 4
    for (int kk = 0; kk < 16; ++kk) {
      bf16x8 hv = *(const bf16x8*)(hbR + kk*512 + m*16);
      #pragma unroll
      for (int j = 0; j < 8; ++j) d += bu2f((u16)hv[j]) * wr[kk*8 + j];
    }
    float v = fsig(d);
    if (o >= 2) v *= 0.5f;
    int s = s0 + m;
    out[(o >= 2 ? 16384 : 0) + s*2 + (o & 1)] = v;
  }
}

extern "C" void kernel_launch(void* const* d_in, const int* in_sizes, int n_in,
                              void* d_out, int out_size, void* d_ws, size_t ws_size,
                              hipStream_t stream) {
  (void)in_sizes; (void)n_in; (void)out_size; (void)ws_size;
  const float* in_tensor = (const float*)d_in[0];
  const float* Wih0 = (const float*)d_in[1];
  const float* Whh0 = (const float*)d_in[2];
  const float* bih0 = (const float*)d_in[3];
  const float* bhh0 = (const float*)d_in[4];
  const float* Wih1 = (const float*)d_in[5];
  const float* Whh1 = (const float*)d_in[6];
  const float* bih1 = (const float*)d_in[7];
  const float* bhh1 = (const float*)d_in[8];
  const float* muW1 = (const float*)d_in[9];
  const float* mub1 = (const float*)d_in[10];
  const float* muW2 = (const float*)d_in[11];
  const float* mub2 = (const float*)d_in[12];
  const float* sgW1 = (const float*)d_in[13];
  const float* sgb1 = (const float*)d_in[14];
  const float* sgW2 = (const float*)d_in[15];
  const float* sgb2 = (const float*)d_in[16];
  unsigned char* ws = (unsigned char*)d_ws;
  float* out = (float*)d_out;

  lstm_prep_w<<<dim3(111), dim3(256), 0, stream>>>(
      Wih0, Whh0, bih0, bhh0, Wih1, Whh1, bih1, bhh1,
      muW1, mub1, muW2, mub2, sgW1, sgb1, sgW2, sgb2, ws);
  lstm_prep_x<<<dim3(2048), dim3(256), 0, stream>>>(in_tensor, ws);

  (void)hipFuncSetAttribute((const void*)lstm_fused,
                            hipFuncAttributeMaxDynamicSharedMemorySize, LDS_BYTES);
  lstm_fused<<<dim3(256), dim3(512), LDS_BYTES, stream>>>(ws, out);
}

// Round 11
// 275.367 us; speedup vs baseline: 1.0296x; 1.0296x over previous
//
#include <hip/hip_runtime.h>
#include <hip/hip_bf16.h>

typedef unsigned short u16;
typedef unsigned int u32;
typedef __attribute__((ext_vector_type(8))) short bf16x8;
typedef __attribute__((ext_vector_type(4))) float f32x4;

#define T_STEPS 64
#define BN_TOT  8192
#define BM      32

// workspace byte offsets
#define OFF_WHH0  0u
#define OFF_WIH0  131072u
#define OFF_W1    163840u
#define OFF_B0    425984u
#define OFF_B1    428032u
#define OFF_WEFF  430080u
#define OFF_BEFF  432128u
#define OFF_XB    432192u

// LDS: whh0 frags (128KB) + hA + hB0 + hB1 (8KB each, col-block-major)
#define HB        8192
#define LDS_BYTES (131072 + 3*HB)   // 155648

__device__ __forceinline__ u16 f2bu(float f) {
  unsigned u = __float_as_uint(f);
  unsigned r = (u + 0x7FFFu + ((u >> 16) & 1u)) >> 16;
  return (u16)r;
}
__device__ __forceinline__ float bu2f(u16 u) {
  return __uint_as_float(((unsigned)u) << 16);
}
__device__ __forceinline__ float fsig(float x) {
  return __builtin_amdgcn_rcpf(1.0f + __builtin_amdgcn_exp2f(-1.44269504f * x));
}
__device__ __forceinline__ unsigned cvt_pk_bf16(float lo, float hi) {
  unsigned r;
  asm("v_cvt_pk_bf16_f32 %0, %1, %2" : "=v"(r) : "v"(lo), "v"(hi));
  return r;
}
__device__ __forceinline__ f32x4 mfma16(bf16x8 a, bf16x8 b, f32x4 c) {
  return __builtin_amdgcn_mfma_f32_16x16x32_bf16(a, b, c, 0, 0, 0);
}

union U16x8 { u16 u[8]; uint4 q; };

// ---------------- prep: weights -> fragment-ordered bf16, collapsed head ----
__global__ void lstm_prep_w(const float* Wih0, const float* Whh0,
                            const float* bih0, const float* bhh0,
                            const float* Wih1, const float* Whh1,
                            const float* bih1, const float* bhh1,
                            const float* muW1, const float* mub1,
                            const float* muW2, const float* mub2,
                            const float* sgW1, const float* sgb1,
                            const float* sgW2, const float* sgb2,
                            unsigned char* ws)
{
  int id = blockIdx.x * 256 + threadIdx.x;
  u16* whh0_f = (u16*)(ws + OFF_WHH0);
  u16* wih0_f = (u16*)(ws + OFF_WIH0);
  u16* w1_f   = (u16*)(ws + OFF_W1);
  float* b0   = (float*)(ws + OFF_B0);
  float* b1   = (float*)(ws + OFF_B1);
  float* weff = (float*)(ws + OFF_WEFF);
  float* beff = (float*)(ws + OFF_BEFF);

  if (id < 8192) {                       // Whh0 frags: [w][g][kf][lane][8]
    int fid = id >> 6, lane = id & 63;
    int w = fid >> 4, g = (fid >> 2) & 3, kf = fid & 3;
    int r = g*128 + w*16 + (lane & 15);
    int k = kf*32 + (lane >> 4)*8;
    const float* src = Whh0 + r*128 + k;
    U16x8 t;
    #pragma unroll
    for (int i = 0; i < 8; ++i) t.u[i] = f2bu(src[i]);
    ((uint4*)whh0_f)[id] = t.q;
  } else if (id < 10240) {               // Wih0 frags (K=8 in 32, zero-padded)
    int c = id - 8192; int fid = c >> 6, lane = c & 63;
    int w = fid >> 2, g = fid & 3;
    U16x8 t;
    #pragma unroll
    for (int i = 0; i < 8; ++i) t.u[i] = 0;
    if (lane < 16) {
      int r = g*128 + w*16 + lane;
      #pragma unroll
      for (int i = 0; i < 8; ++i) t.u[i] = f2bu(Wih0[r*8 + i]);
    }
    ((uint4*)wih0_f)[c] = t.q;
  } else if (id < 26624) {               // W1 = [Wih1 ; Whh1] frags, K=256
    int c = id - 10240; int fid = c >> 6, lane = c & 63;
    int w = fid >> 5, g = (fid >> 3) & 3, kf = fid & 7;
    int r = g*128 + w*16 + (lane & 15);
    int k = kf*32 + (lane >> 4)*8;
    const float* src = (k < 128) ? (Wih1 + r*128 + k) : (Whh1 + r*128 + (k-128));
    U16x8 t;
    #pragma unroll
    for (int i = 0; i < 8; ++i) t.u[i] = f2bu(src[i]);
    ((uint4*)w1_f)[c] = t.q;
  } else if (id < 27136) {               // b0 arranged
    int i = id - 26624; int w = i >> 6, g = (i >> 4) & 3, cc = i & 15;
    int r = g*128 + w*16 + cc;
    b0[i] = bih0[r] + bhh0[r];
  } else if (id < 27648) {               // b1 arranged
    int i = id - 27136; int w = i >> 6, g = (i >> 4) & 3, cc = i & 15;
    int r = g*128 + w*16 + cc;
    b1[i] = bih1[r] + bhh1[r];
  } else if (id < 28160) {               // collapsed head W: [4][128]
    int i = id - 27648; int o = i >> 7, k = i & 127;
    const float* W1p = (o < 2) ? muW1 : sgW1;
    const float* W2p = (o < 2) ? muW2 : sgW2;
    int oo = o & 1;
    float s = 0.f;
    for (int m = 0; m < 64; ++m) s += W2p[oo*64 + m] * W1p[m*128 + k];
    weff[i] = s;
  } else if (id < 28164) {               // collapsed head bias [4]
    int o = id - 28160; int oo = o & 1;
    const float* W2p = (o < 2) ? muW2 : sgW2;
    const float* b1p = (o < 2) ? mub1 : sgb1;
    const float* b2p = (o < 2) ? mub2 : sgb2;
    float s = b2p[oo];
    for (int m = 0; m < 64; ++m) s += W2p[oo*64 + m] * b1p[m];
    beff[o] = s;
  }
}

// ---------------- prep: in_tensor [B,T,N,D] fp32 -> xb [T, BN, 8] bf16 ------
__global__ void lstm_prep_x(const float* in, unsigned char* ws)
{
  int id = blockIdx.x * 256 + threadIdx.x;     // < 524288
  if (id >= T_STEPS * BN_TOT) return;
  int t = id >> 13, s = id & 8191, b = s >> 9, n = s & 511;
  const float* src = in + (((b*64) + t)*512 + n)*8;
  U16x8 v;
  #pragma unroll
  for (int i = 0; i < 8; ++i) v.u[i] = f2bu(src[i]);
  *(uint4*)(ws + OFF_XB + (size_t)id * 16) = v.q;
}

// ---------------- main: fused 2-layer LSTM + head ---------------------------
// R11 = R9 (best: 270us) + shared-denominator ACT + 2 barriers/step.
// bias-as-C reverted (R10: +32 live VGPRs -> +2.5MB spill, net loss).
// ACT algebra (exact):
//   c = [c_prev*a1*a3 + (1-eg)*a2] * rcp(a1*a2*a3),  a_i = 1+exp(-gate)
//   h = (1-ec) * rcp((1+eo)*(1+ec)),                 ec  = exp(-2*clamp(c))
// 5 exp + 2 rcp per cell (was 5+5); leading exps independent.
// h layout: col-block-major, addr(row,col) = (col>>3)*512 + row*16 + (col&7)*2
#define ACT_BLOCK(ACC, CS, HBASE)                                          \
  { _Pragma("unroll")                                                      \
    for (int mf = 0; mf < 2; ++mf) {                                       \
      float hq[4];                                                         \
      _Pragma("unroll")                                                    \
      for (int q = 0; q < 4; ++q) {                                        \
        float ei = __builtin_amdgcn_exp2f(-1.44269504f * ACC[mf][0][q]);   \
        float ef = __builtin_amdgcn_exp2f(-1.44269504f * ACC[mf][1][q]);   \
        float eg = __builtin_amdgcn_exp2f(-2.88539008f * ACC[mf][2][q]);   \
        float eo = __builtin_amdgcn_exp2f(-1.44269504f * ACC[mf][3][q]);   \
        float a1 = 1.0f + ei, a2 = 1.0f + ef, a3 = 1.0f + eg;              \
        float p13 = a1 * a3;                                               \
        float num = fmaf(CS[mf][q], p13, (1.0f - eg) * a2);                \
        float c = num * __builtin_amdgcn_rcpf(p13 * a2);                   \
        CS[mf][q] = c;                                                     \
        float cc = fminf(fmaxf(c, -40.0f), 40.0f);                         \
        float ec = __builtin_amdgcn_exp2f(-2.88539008f * cc);              \
        hq[q] = (1.0f - ec) * __builtin_amdgcn_rcpf((1.0f + eo) * (1.0f + ec)); \
      }                                                                    \
      unsigned p01 = cvt_pk_bf16(hq[0], hq[1]);                            \
      unsigned p23 = cvt_pk_bf16(hq[2], hq[3]);                            \
      int rb = (mf*16 + lk*4);                                             \
      *(u16*)((HBASE) + wb + (rb  )*16) = (u16)p01;                        \
      *(u16*)((HBASE) + wb + (rb+1)*16) = (u16)(p01 >> 16);                \
      *(u16*)((HBASE) + wb + (rb+2)*16) = (u16)p23;                        \
      *(u16*)((HBASE) + wb + (rb+3)*16) = (u16)(p23 >> 16);                \
    } }

__global__ __launch_bounds__(512, 2) void lstm_fused(const unsigned char* ws, float* out)
{
  extern __shared__ unsigned char lds[];
  u16* whh0_lds = (u16*)lds;                 // [w][g][kf][lane][8] frags, 128KB
  unsigned char* hA  = lds + 131072;
  unsigned char* hB0 = hA + HB;
  unsigned char* hB1 = hB0 + HB;

  const u16* whh0_f = (const u16*)(ws + OFF_WHH0);
  const u16* wih0_f = (const u16*)(ws + OFF_WIH0);
  const u16* w1_f   = (const u16*)(ws + OFF_W1);
  const float* b0a  = (const float*)(ws + OFF_B0);
  const float* b1a  = (const float*)(ws + OFF_B1);
  const float* weff = (const float*)(ws + OFF_WEFF);
  const float* beff = (const float*)(ws + OFF_BEFF);
  const u16* xb     = (const u16*)(ws + OFF_XB);

  const int tid = threadIdx.x;
  const int w = tid >> 6, l = tid & 63;
  const int lrow = l & 15, lk = l >> 4;
  const int s0 = blockIdx.x * BM;
  const int wb = (w*2 + (lrow >> 3))*512 + (lrow & 7)*2;   // ACT write base

  // stage Whh0 frags into LDS (straight 16B copies, layout identical)
  for (int i = tid; i < 8192; i += 512)
    ((uint4*)whh0_lds)[i] = ((const uint4*)whh0_f)[i];
  // zero all three h buffers (contiguous 24KB)
  for (int i = tid; i < 6144; i += 512) ((u32*)hA)[i] = 0;

  // persistent register weights (plain arrays, builtin consumers: compiler
  // promotes w1r to AGPRs itself -- R2/R9 evidence)
  bf16x8 w1r[4][8];
  #pragma unroll
  for (int g = 0; g < 4; ++g)
    #pragma unroll
    for (int kf = 0; kf < 8; ++kf)
      w1r[g][kf] = *(const bf16x8*)(w1_f + ((((w*4+g)*8)+kf)*64 + l)*8);
  bf16x8 wih0r[4];
  #pragma unroll
  for (int g = 0; g < 4; ++g)
    wih0r[g] = *(const bf16x8*)(wih0_f + ((w*4+g)*64 + l)*8);
  float b0v[4], b1v[4];
  #pragma unroll
  for (int g = 0; g < 4; ++g) {
    b0v[g] = b0a[w*64 + g*16 + lrow];
    b1v[g] = b1a[w*64 + g*16 + lrow];
  }
  float c_a[2][4] = {{0,0,0,0},{0,0,0,0}};
  float c_b[2][4] = {{0,0,0,0},{0,0,0,0}};

  unsigned char* hbR = hB0;   // layer-1 h_prev (zero at t=0)
  unsigned char* hbW = hB1;

  // x software pipeline: xf holds step t's fragment; loaded one phase early
  bf16x8 xf0 = {0,0,0,0,0,0,0,0}, xf1 = {0,0,0,0,0,0,0,0};
  if (lk == 0) {
    xf0 = *(const bf16x8*)(xb + (size_t)(s0 + lrow)*8);
    xf1 = *(const bf16x8*)(xb + (size_t)(s0 + 16 + lrow)*8);
  }
  __syncthreads();

  #pragma unroll 1
  for (int t = 0; t < T_STEPS; ++t) {
    // ---- seg1: L0m(t) = b0 + x@Wih0^T + hA@Whh0^T --------------------------
    f32x4 acc[2][4];
    #pragma unroll
    for (int g = 0; g < 4; ++g) {
      acc[0][g] = (f32x4){b0v[g], b0v[g], b0v[g], b0v[g]};
      acc[1][g] = (f32x4){b0v[g], b0v[g], b0v[g], b0v[g]};
    }
    #pragma unroll
    for (int g = 0; g < 4; ++g) {
      acc[0][g] = mfma16(xf0, wih0r[g], acc[0][g]);
      acc[1][g] = mfma16(xf1, wih0r[g], acc[1][g]);
    }
    // prefetch next step's x (L2 latency hides under the rest of the step)
    if (t + 1 < T_STEPS && lk == 0) {
      xf0 = *(const bf16x8*)(xb + (size_t)((t+1)*8192 + s0 + lrow)*8);
      xf1 = *(const bf16x8*)(xb + (size_t)((t+1)*8192 + s0 + 16 + lrow)*8);
    }
    #pragma unroll
    for (int kf = 0; kf < 4; ++kf) {
      bf16x8 a0 = *(const bf16x8*)(hA + (kf*4 + lk)*512 + lrow*16);
      bf16x8 a1 = *(const bf16x8*)(hA + (kf*4 + lk)*512 + (16 + lrow)*16);
      #pragma unroll
      for (int g = 0; g < 4; ++g) {
        bf16x8 bfr = *(const bf16x8*)(whh0_lds + ((w*16 + g*4 + kf)*64 + l)*8);
        acc[0][g] = mfma16(a0, bfr, acc[0][g]);
        acc[1][g] = mfma16(a1, bfr, acc[1][g]);
      }
    }
    __syncthreads();                       // bar1: hA reads + prior hB writes done
    // ---- seg2: ACT0(t) -> hA(t) -------------------------------------------
    ACT_BLOCK(acc, c_a, hA);
    __syncthreads();                       // bar2: hA(t) visible

    // ---- seg3: L1m(t) = b1 + hA@Wih1^T + hbR@Whh1^T, then ACT1(t) ---------
    #pragma unroll
    for (int g = 0; g < 4; ++g) {
      acc[0][g] = (f32x4){b1v[g], b1v[g], b1v[g], b1v[g]};
      acc[1][g] = (f32x4){b1v[g], b1v[g], b1v[g], b1v[g]};
    }
    #pragma unroll
    for (int kf = 0; kf < 8; ++kf) {
      const unsigned char* hs = (kf < 4) ? hA : hbR;
      bf16x8 a0 = *(const bf16x8*)(hs + ((kf & 3)*4 + lk)*512 + lrow*16);
      bf16x8 a1 = *(const bf16x8*)(hs + ((kf & 3)*4 + lk)*512 + (16 + lrow)*16);
      #pragma unroll
      for (int g = 0; g < 4; ++g) {
        acc[0][g] = mfma16(a0, w1r[g][kf], acc[0][g]);
        acc[1][g] = mfma16(a1, w1r[g][kf], acc[1][g]);
      }
    }
    // ACT1 writes hbW (ping-pong): RAW to L1m(t+1) crosses bar1+bar2 of t+1;
    // WAR on hbR blocked by bar1(t+1). No barrier here (verified R10).
    ACT_BLOCK(acc, c_b, hbW);
    { unsigned char* tp = hbR; hbR = hbW; hbW = tp; }
  }
  __syncthreads();                         // final hB visible for the head

  // ---- head: out = sigmoid(h_final @ Weff^T + beff), sigma *= 0.5 ----------
  if (tid < BM*4) {
    int m = tid >> 2, o = tid & 3;
    const float* wr = weff + o*128;
    float d = beff[o];
    #pragma unroll 4
    for (int kk = 0; kk < 16; ++kk) {
      bf16x8 hv = *(const bf16x8*)(hbR + kk*512 + m*16);
      #pragma unroll
      for (int j = 0; j < 8; ++j) d += bu2f((u16)hv[j]) * wr[kk*8 + j];
    }
    float v = fsig(d);
    if (o >= 2) v *= 0.5f;
    int s = s0 + m;
    out[(o >= 2 ? 16384 : 0) + s*2 + (o & 1)] = v;
  }
}

extern "C" void kernel_launch(void* const* d_in, const int* in_sizes, int n_in,
                              void* d_out, int out_size, void* d_ws, size_t ws_size,
                              hipStream_t stream) {
  (void)in_sizes; (void)n_in; (void)out_size; (void)ws_size;
  const float* in_tensor = (const float*)d_in[0];
  const float* Wih0 = (const float*)d_in[1];
  const float* Whh0 = (const float*)d_in[2];
  const float* bih0 = (const float*)d_in[3];
  const float* bhh0 = (const float*)d_in[4];
  const float* Wih1 = (const float*)d_in[5];
  const float* Whh1 = (const float*)d_in[6];
  const float* bih1 = (const float*)d_in[7];
  const float* bhh1 = (const float*)d_in[8];
  const float* muW1 = (const float*)d_in[9];
  const float* mub1 = (const float*)d_in[10];
  const float* muW2 = (const float*)d_in[11];
  const float* mub2 = (const float*)d_in[12];
  const float* sgW1 = (const float*)d_in[13];
  const float* sgb1 = (const float*)d_in[14];
  const float* sgW2 = (const float*)d_in[15];
  const float* sgb2 = (const float*)d_in[16];
  unsigned char* ws = (unsigned char*)d_ws;
  float* out = (float*)d_out;

  lstm_prep_w<<<dim3(111), dim3(256), 0, stream>>>(
      Wih0, Whh0, bih0, bhh0, Wih1, Whh1, bih1, bhh1,
      muW1, mub1, muW2, mub2, sgW1, sgb1, sgW2, sgb2, ws);
  lstm_prep_x<<<dim3(2048), dim3(256), 0, stream>>>(in_tensor, ws);

  (void)hipFuncSetAttribute((const void*)lstm_fused,
                            hipFuncAttributeMaxDynamicSharedMemorySize, LDS_BYTES);
  lstm_fused<<<dim3(256), dim3(512), LDS_BYTES, stream>>>(ws, out);
}

// Round 12
// 234.046 us; speedup vs baseline: 1.2114x; 1.1766x over previous
//
#include <hip/hip_runtime.h>
#include <hip/hip_bf16.h>

typedef unsigned short u16;
typedef unsigned int u32;
typedef __attribute__((ext_vector_type(8))) short bf16x8;
typedef __attribute__((ext_vector_type(4))) float f32x4;

#define T_STEPS 64
#define BN_TOT  8192
#define BM      32

// workspace byte offsets
#define OFF_WHH0  0u
#define OFF_WIH0  131072u
#define OFF_W1    163840u
#define OFF_B0    425984u
#define OFF_B1    428032u
#define OFF_WEFF  430080u
#define OFF_BEFF  432128u
#define OFF_XB    432192u

// LDS: whh0 frags (128KB) + 4 h buffers (8KB each) = 160KiB exactly
#define HB        8192
#define LDS_BYTES (131072 + 4*HB)   // 163840

__device__ __forceinline__ u16 f2bu(float f) {
  unsigned u = __float_as_uint(f);
  unsigned r = (u + 0x7FFFu + ((u >> 16) & 1u)) >> 16;
  return (u16)r;
}
__device__ __forceinline__ float bu2f(u16 u) {
  return __uint_as_float(((unsigned)u) << 16);
}
__device__ __forceinline__ float fsig(float x) {
  return __builtin_amdgcn_rcpf(1.0f + __builtin_amdgcn_exp2f(-1.44269504f * x));
}
__device__ __forceinline__ unsigned cvt_pk_bf16(float lo, float hi) {
  unsigned r;
  asm("v_cvt_pk_bf16_f32 %0, %1, %2" : "=v"(r) : "v"(lo), "v"(hi));
  return r;
}
__device__ __forceinline__ f32x4 mfma16(bf16x8 a, bf16x8 b, f32x4 c) {
  return __builtin_amdgcn_mfma_f32_16x16x32_bf16(a, b, c, 0, 0, 0);
}

union U16x8 { u16 u[8]; uint4 q; };

// ---------------- prep: weights -> fragment-ordered bf16, collapsed head ----
__global__ void lstm_prep_w(const float* Wih0, const float* Whh0,
                            const float* bih0, const float* bhh0,
                            const float* Wih1, const float* Whh1,
                            const float* bih1, const float* bhh1,
                            const float* muW1, const float* mub1,
                            const float* muW2, const float* mub2,
                            const float* sgW1, const float* sgb1,
                            const float* sgW2, const float* sgb2,
                            unsigned char* ws)
{
  int id = blockIdx.x * 256 + threadIdx.x;
  u16* whh0_f = (u16*)(ws + OFF_WHH0);
  u16* wih0_f = (u16*)(ws + OFF_WIH0);
  u16* w1_f   = (u16*)(ws + OFF_W1);
  float* b0   = (float*)(ws + OFF_B0);
  float* b1   = (float*)(ws + OFF_B1);
  float* weff = (float*)(ws + OFF_WEFF);
  float* beff = (float*)(ws + OFF_BEFF);

  if (id < 8192) {                       // Whh0 frags: [w][g][kf][lane][8]
    int fid = id >> 6, lane = id & 63;
    int w = fid >> 4, g = (fid >> 2) & 3, kf = fid & 3;
    int r = g*128 + w*16 + (lane & 15);
    int k = kf*32 + (lane >> 4)*8;
    const float* src = Whh0 + r*128 + k;
    U16x8 t;
    #pragma unroll
    for (int i = 0; i < 8; ++i) t.u[i] = f2bu(src[i]);
    ((uint4*)whh0_f)[id] = t.q;
  } else if (id < 10240) {               // Wih0 frags (K=8 in 32, zero-padded)
    int c = id - 8192; int fid = c >> 6, lane = c & 63;
    int w = fid >> 2, g = fid & 3;
    U16x8 t;
    #pragma unroll
    for (int i = 0; i < 8; ++i) t.u[i] = 0;
    if (lane < 16) {
      int r = g*128 + w*16 + lane;
      #pragma unroll
      for (int i = 0; i < 8; ++i) t.u[i] = f2bu(Wih0[r*8 + i]);
    }
    ((uint4*)wih0_f)[c] = t.q;
  } else if (id < 26624) {               // W1 = [Wih1 ; Whh1] frags, K=256
    int c = id - 10240; int fid = c >> 6, lane = c & 63;
    int w = fid >> 5, g = (fid >> 3) & 3, kf = fid & 7;
    int r = g*128 + w*16 + (lane & 15);
    int k = kf*32 + (lane >> 4)*8;
    const float* src = (k < 128) ? (Wih1 + r*128 + k) : (Whh1 + r*128 + (k-128));
    U16x8 t;
    #pragma unroll
    for (int i = 0; i < 8; ++i) t.u[i] = f2bu(src[i]);
    ((uint4*)w1_f)[c] = t.q;
  } else if (id < 27136) {               // b0 arranged
    int i = id - 26624; int w = i >> 6, g = (i >> 4) & 3, cc = i & 15;
    int r = g*128 + w*16 + cc;
    b0[i] = bih0[r] + bhh0[r];
  } else if (id < 27648) {               // b1 arranged
    int i = id - 27136; int w = i >> 6, g = (i >> 4) & 3, cc = i & 15;
    int r = g*128 + w*16 + cc;
    b1[i] = bih1[r] + bhh1[r];
  } else if (id < 28160) {               // collapsed head W: [4][128]
    int i = id - 27648; int o = i >> 7, k = i & 127;
    const float* W1p = (o < 2) ? muW1 : sgW1;
    const float* W2p = (o < 2) ? muW2 : sgW2;
    int oo = o & 1;
    float s = 0.f;
    for (int m = 0; m < 64; ++m) s += W2p[oo*64 + m] * W1p[m*128 + k];
    weff[i] = s;
  } else if (id < 28164) {               // collapsed head bias [4]
    int o = id - 28160; int oo = o & 1;
    const float* W2p = (o < 2) ? muW2 : sgW2;
    const float* b1p = (o < 2) ? mub1 : sgb1;
    const float* b2p = (o < 2) ? mub2 : sgb2;
    float s = b2p[oo];
    for (int m = 0; m < 64; ++m) s += W2p[oo*64 + m] * b1p[m];
    beff[o] = s;
  }
}

// ---------------- prep: in_tensor [B,T,N,D] fp32 -> xb [T, BN, 8] bf16 ------
__global__ void lstm_prep_x(const float* in, unsigned char* ws)
{
  int id = blockIdx.x * 256 + threadIdx.x;     // < 524288
  if (id >= T_STEPS * BN_TOT) return;
  int t = id >> 13, s = id & 8191, b = s >> 9, n = s & 511;
  const float* src = in + (((b*64) + t)*512 + n)*8;
  U16x8 v;
  #pragma unroll
  for (int i = 0; i < 8; ++i) v.u[i] = f2bu(src[i]);
  *(uint4*)(ws + OFF_XB + (size_t)id * 16) = v.q;
}

// ---------------- main: fused 2-layer LSTM + head ---------------------------
// R12 = R11 + single-barrier rotated schedule with hA AND hB double-buffered.
//   hA(t) -> bufA[t&1], hB(t) -> bufB[t&1].
//   body(t) = [L1m(t); ACT1(t)->bufB[t&1]; load x(t+1);
//              L0m(t+1); ACT0(t+1)->bufA[(t+1)&1]; BAR]
// Hazards (all cross >=1 BAR):
//   RAW ACT0(t)->L1m(t)/L0m(t+1): ACT0(t) before BAR(t); readers after.
//   RAW ACT1(t)->L1m(t+1): crosses BAR(t).
//   WAR ACT0(t+1) vs readers of bufA[(t+1)&1] (= L1m(t-1), L0m(t)): those
//     reads complete before BAR(t); ACT0(t+1) is after BAR(t).
//   WAR ACT1(t) vs L1m(t-1)'s read of bufB[t&1]: crosses BAR(t).
// ACT1(t) (VALU/trans) and L0m(t+1) (MFMA) share one basic block -> the
// scheduler may interleave them; acc1 is born and dies within one body
// (no live-across-back-edge accumulator -- R8's spill mode avoided).
// ACT algebra (exact, R10/R11-verified):
//   c = [c_prev*a1*a3 + (1-eg)*a2] * rcp(a1*a2*a3),  a_i = 1+exp(-gate)
//   h = (1-ec) * rcp((1+eo)*(1+ec)),                 ec  = exp(-2*clamp(c))
// h layout: col-block-major, addr(row,col) = (col>>3)*512 + row*16 + (col&7)*2
#define ACT_BLOCK(ACC, CS, HBASE)                                          \
  { _Pragma("unroll")                                                      \
    for (int mf = 0; mf < 2; ++mf) {                                       \
      float hq[4];                                                         \
      _Pragma("unroll")                                                    \
      for (int q = 0; q < 4; ++q) {                                        \
        float ei = __builtin_amdgcn_exp2f(-1.44269504f * ACC[mf][0][q]);   \
        float ef = __builtin_amdgcn_exp2f(-1.44269504f * ACC[mf][1][q]);   \
        float eg = __builtin_amdgcn_exp2f(-2.88539008f * ACC[mf][2][q]);   \
        float eo = __builtin_amdgcn_exp2f(-1.44269504f * ACC[mf][3][q]);   \
        float a1 = 1.0f + ei, a2 = 1.0f + ef, a3 = 1.0f + eg;              \
        float p13 = a1 * a3;                                               \
        float num = fmaf(CS[mf][q], p13, (1.0f - eg) * a2);                \
        float c = num * __builtin_amdgcn_rcpf(p13 * a2);                   \
        CS[mf][q] = c;                                                     \
        float cc = fminf(fmaxf(c, -40.0f), 40.0f);                         \
        float ec = __builtin_amdgcn_exp2f(-2.88539008f * cc);              \
        hq[q] = (1.0f - ec) * __builtin_amdgcn_rcpf((1.0f + eo) * (1.0f + ec)); \
      }                                                                    \
      unsigned p01 = cvt_pk_bf16(hq[0], hq[1]);                            \
      unsigned p23 = cvt_pk_bf16(hq[2], hq[3]);                            \
      int rb = (mf*16 + lk*4);                                             \
      *(u16*)((HBASE) + wb + (rb  )*16) = (u16)p01;                        \
      *(u16*)((HBASE) + wb + (rb+1)*16) = (u16)(p01 >> 16);                \
      *(u16*)((HBASE) + wb + (rb+2)*16) = (u16)p23;                        \
      *(u16*)((HBASE) + wb + (rb+3)*16) = (u16)(p23 >> 16);                \
    } }

__global__ __launch_bounds__(512, 2) void lstm_fused(const unsigned char* ws, float* out)
{
  extern __shared__ unsigned char lds[];
  u16* whh0_lds = (u16*)lds;                 // [w][g][kf][lane][8] frags, 128KB
  unsigned char* hA0 = lds + 131072;
  unsigned char* hA1 = hA0 + HB;
  unsigned char* hB0 = hA1 + HB;
  unsigned char* hB1 = hB0 + HB;

  const u16* whh0_f = (const u16*)(ws + OFF_WHH0);
  const u16* wih0_f = (const u16*)(ws + OFF_WIH0);
  const u16* w1_f   = (const u16*)(ws + OFF_W1);
  const float* b0a  = (const float*)(ws + OFF_B0);
  const float* b1a  = (const float*)(ws + OFF_B1);
  const float* weff = (const float*)(ws + OFF_WEFF);
  const float* beff = (const float*)(ws + OFF_BEFF);
  const u16* xb     = (const u16*)(ws + OFF_XB);

  const int tid = threadIdx.x;
  const int w = tid >> 6, l = tid & 63;
  const int lrow = l & 15, lk = l >> 4;
  const int s0 = blockIdx.x * BM;
  const int wb = (w*2 + (lrow >> 3))*512 + (lrow & 7)*2;   // ACT write base

  // stage Whh0 frags into LDS (straight 16B copies, layout identical)
  for (int i = tid; i < 8192; i += 512)
    ((uint4*)whh0_lds)[i] = ((const uint4*)whh0_f)[i];
  // zero all four h buffers (contiguous 32KB)
  for (int i = tid; i < 8192; i += 512) ((u32*)hA0)[i] = 0;

  // persistent register weights (plain arrays, builtin consumers: compiler
  // promotes w1r to AGPRs itself -- R2/R9/R11 evidence)
  bf16x8 w1r[4][8];
  #pragma unroll
  for (int g = 0; g < 4; ++g)
    #pragma unroll
    for (int kf = 0; kf < 8; ++kf)
      w1r[g][kf] = *(const bf16x8*)(w1_f + ((((w*4+g)*8)+kf)*64 + l)*8);
  bf16x8 wih0r[4];
  #pragma unroll
  for (int g = 0; g < 4; ++g)
    wih0r[g] = *(const bf16x8*)(wih0_f + ((w*4+g)*64 + l)*8);
  float b0v[4], b1v[4];
  #pragma unroll
  for (int g = 0; g < 4; ++g) {
    b0v[g] = b0a[w*64 + g*16 + lrow];
    b1v[g] = b1a[w*64 + g*16 + lrow];
  }
  float c_a[2][4] = {{0,0,0,0},{0,0,0,0}};
  float c_b[2][4] = {{0,0,0,0},{0,0,0,0}};

  // pointer roles at loop iter t: aR = bufA[t&1] (read by L1m(t), L0m(t+1)),
  // aW = bufA[1-(t&1)] (ACT0(t+1) dst), bR = bufB[1-(t&1)], bW = bufB[t&1].
  unsigned char *aR = hA0, *aW = hA1, *bR = hB1, *bW = hB0;

  __syncthreads();

  // ---- peel: L0m(0) on hA(-1)=bufA[1]=0, ACT0(0)->bufA[0] ------------------
  {
    const u16* xrow = xb + (size_t)(s0 + lrow)*8;
    bf16x8 xf0 = *(const bf16x8*)xrow;          // lanes lk>0: B rows >=8 are 0
    bf16x8 xf1 = *(const bf16x8*)(xrow + 128);
    f32x4 acc0[2][4];
    #pragma unroll
    for (int g = 0; g < 4; ++g) {
      acc0[0][g] = (f32x4){b0v[g], b0v[g], b0v[g], b0v[g]};
      acc0[1][g] = (f32x4){b0v[g], b0v[g], b0v[g], b0v[g]};
    }
    #pragma unroll
    for (int g = 0; g < 4; ++g) {
      acc0[0][g] = mfma16(xf0, wih0r[g], acc0[0][g]);
      acc0[1][g] = mfma16(xf1, wih0r[g], acc0[1][g]);
    }
    // hA(-1) is zero: skip the 32 hh-MFMAs
    ACT_BLOCK(acc0, c_a, aR);                   // hA(0) -> bufA[0]
  }
  __syncthreads();                              // BAR(-1->0): hA(0) visible

  // ---- main loop t = 0..62: one barrier per step ---------------------------
  #pragma unroll 1
  for (int t = 0; t < T_STEPS - 1; ++t) {
    // L1m(t): b1 + hA(t)@Wih1 + hB(t-1)@Whh1  (W1 in AGPRs)
    f32x4 acc1[2][4];
    #pragma unroll
    for (int g = 0; g < 4; ++g) {
      acc1[0][g] = (f32x4){b1v[g], b1v[g], b1v[g], b1v[g]};
      acc1[1][g] = (f32x4){b1v[g], b1v[g], b1v[g], b1v[g]};
    }
    #pragma unroll
    for (int kf = 0; kf < 8; ++kf) {
      const unsigned char* hs = (kf < 4) ? aR : bR;
      bf16x8 a0 = *(const bf16x8*)(hs + ((kf & 3)*4 + lk)*512 + lrow*16);
      bf16x8 a1 = *(const bf16x8*)(hs + ((kf & 3)*4 + lk)*512 + (16 + lrow)*16);
      #pragma unroll
      for (int g = 0; g < 4; ++g) {
        acc1[0][g] = mfma16(a0, w1r[g][kf], acc1[0][g]);
        acc1[1][g] = mfma16(a1, w1r[g][kf], acc1[1][g]);
      }
    }
    ACT_BLOCK(acc1, c_b, bW);                   // hB(t) -> bufB[t&1]

    // x(t+1) (L2-resident; latency hidden under surrounding MFMAs)
    const u16* xrow = xb + (size_t)((t+1)*8192 + s0 + lrow)*8;
    bf16x8 xf0 = *(const bf16x8*)xrow;
    bf16x8 xf1 = *(const bf16x8*)(xrow + 128);

    // L0m(t+1): b0 + x(t+1)@Wih0 + hA(t)@Whh0 -- independent of ACT1(t),
    // same basic block -> scheduler may overlap ACT1 VALU with these MFMAs.
    f32x4 acc0[2][4];
    #pragma unroll
    for (int g = 0; g < 4; ++g) {
      acc0[0][g] = (f32x4){b0v[g], b0v[g], b0v[g], b0v[g]};
      acc0[1][g] = (f32x4){b0v[g], b0v[g], b0v[g], b0v[g]};
    }
    #pragma unroll
    for (int g = 0; g < 4; ++g) {
      acc0[0][g] = mfma16(xf0, wih0r[g], acc0[0][g]);
      acc0[1][g] = mfma16(xf1, wih0r[g], acc0[1][g]);
    }
    #pragma unroll
    for (int kf = 0; kf < 4; ++kf) {
      bf16x8 a0 = *(const bf16x8*)(aR + (kf*4 + lk)*512 + lrow*16);
      bf16x8 a1 = *(const bf16x8*)(aR + (kf*4 + lk)*512 + (16 + lrow)*16);
      #pragma unroll
      for (int g = 0; g < 4; ++g) {
        bf16x8 bfr = *(const bf16x8*)(whh0_lds + ((w*16 + g*4 + kf)*64 + l)*8);
        acc0[0][g] = mfma16(a0, bfr, acc0[0][g]);
        acc0[1][g] = mfma16(a1, bfr, acc0[1][g]);
      }
    }
    ACT_BLOCK(acc0, c_a, aW);                   // hA(t+1) -> bufA[(t+1)&1]

    __syncthreads();                            // the ONE barrier per step
    { unsigned char* tp = aR; aR = aW; aW = tp; }
    { unsigned char* tp = bR; bR = bW; bW = tp; }
  }

  // ---- epilogue: L1m(63) + ACT1(63) -> bW = bufB[1] ------------------------
  {
    f32x4 acc1[2][4];
    #pragma unroll
    for (int g = 0; g < 4; ++g) {
      acc1[0][g] = (f32x4){b1v[g], b1v[g], b1v[g], b1v[g]};
      acc1[1][g] = (f32x4){b1v[g], b1v[g], b1v[g], b1v[g]};
    }
    #pragma unroll
    for (int kf = 0; kf < 8; ++kf) {
      const unsigned char* hs = (kf < 4) ? aR : bR;
      bf16x8 a0 = *(const bf16x8*)(hs + ((kf & 3)*4 + lk)*512 + lrow*16);
      bf16x8 a1 = *(const bf16x8*)(hs + ((kf & 3)*4 + lk)*512 + (16 + lrow)*16);
      #pragma unroll
      for (int g = 0; g < 4; ++g) {
        acc1[0][g] = mfma16(a0, w1r[g][kf], acc1[0][g]);
        acc1[1][g] = mfma16(a1, w1r[g][kf], acc1[1][g]);
      }
    }
    ACT_BLOCK(acc1, c_b, bW);
  }
  __syncthreads();                              // final hB visible for head

  // ---- head: out = sigmoid(h_final @ Weff^T + beff), sigma *= 0.5 ----------
  if (tid < BM*4) {
    int m = tid >> 2, o = tid & 3;
    const float* wr = weff + o*128;
    float d = beff[o];
    #pragma unroll 4
    for (int kk = 0; kk < 16; ++kk) {
      bf16x8 hv = *(const bf16x8*)(bW + kk*512 + m*16);
      #pragma unroll
      for (int j = 0; j < 8; ++j) d += bu2f((u16)hv[j]) * wr[kk*8 + j];
    }
    float v = fsig(d);
    if (o >= 2) v *= 0.5f;
    int s = s0 + m;
    out[(o >= 2 ? 16384 : 0) + s*2 + (o & 1)] = v;
  }
}

extern "C" void kernel_launch(void* const* d_in, const int* in_sizes, int n_in,
                              void* d_out, int out_size, void* d_ws, size_t ws_size,
                              hipStream_t stream) {
  (void)in_sizes; (void)n_in; (void)out_size; (void)ws_size;
  const float* in_tensor = (const float*)d_in[0];
  const float* Wih0 = (const float*)d_in[1];
  const float* Whh0 = (const float*)d_in[2];
  const float* bih0 = (const float*)d_in[3];
  const float* bhh0 = (const float*)d_in[4];
  const float* Wih1 = (const float*)d_in[5];
  const float* Whh1 = (const float*)d_in[6];
  const float* bih1 = (const float*)d_in[7];
  const float* bhh1 = (const float*)d_in[8];
  const float* muW1 = (const float*)d_in[9];
  const float* mub1 = (const float*)d_in[10];
  const float* muW2 = (const float*)d_in[11];
  const float* mub2 = (const float*)d_in[12];
  const float* sgW1 = (const float*)d_in[13];
  const float* sgb1 = (const float*)d_in[14];
  const float* sgW2 = (const float*)d_in[15];
  const float* sgb2 = (const float*)d_in[16];
  unsigned char* ws = (unsigned char*)d_ws;
  float* out = (float*)d_out;

  lstm_prep_w<<<dim3(111), dim3(256), 0, stream>>>(
      Wih0, Whh0, bih0, bhh0, Wih1, Whh1, bih1, bhh1,
      muW1, mub1, muW2, mub2, sgW1, sgb1, sgW2, sgb2, ws);
  lstm_prep_x<<<dim3(2048), dim3(256), 0, stream>>>(in_tensor, ws);

  (void)hipFuncSetAttribute((const void*)lstm_fused,
                            hipFuncAttributeMaxDynamicSharedMemorySize, LDS_BYTES);
  lstm_fused<<<dim3(256), dim3(512), LDS_BYTES, stream>>>(ws, out);
}

// Round 13
// 232.800 us; speedup vs baseline: 1.2179x; 1.0054x over previous
//
#include <hip/hip_runtime.h>
#include <hip/hip_bf16.h>

typedef unsigned short u16;
typedef unsigned int u32;
typedef __attribute__((ext_vector_type(8))) short bf16x8;
typedef __attribute__((ext_vector_type(4))) float f32x4;

#define T_STEPS 64
#define BN_TOT  8192
#define BM      32

// workspace byte offsets
#define OFF_WHH0  0u
#define OFF_WIH0  131072u
#define OFF_W1    163840u
#define OFF_B0    425984u
#define OFF_B1    428032u
#define OFF_WEFF  430080u
#define OFF_BEFF  432128u
#define OFF_XB    432192u

// LDS: whh0 frags (128KB) + 4 h buffers (8KB each) = 160KiB exactly
#define HB        8192
#define LDS_BYTES (131072 + 4*HB)   // 163840

__device__ __forceinline__ u16 f2bu(float f) {
  unsigned u = __float_as_uint(f);
  unsigned r = (u + 0x7FFFu + ((u >> 16) & 1u)) >> 16;
  return (u16)r;
}
__device__ __forceinline__ float bu2f(u16 u) {
  return __uint_as_float(((unsigned)u) << 16);
}
__device__ __forceinline__ float fsig(float x) {
  return __builtin_amdgcn_rcpf(1.0f + __builtin_amdgcn_exp2f(-1.44269504f * x));
}
__device__ __forceinline__ unsigned cvt_pk_bf16(float lo, float hi) {
  unsigned r;
  asm("v_cvt_pk_bf16_f32 %0, %1, %2" : "=v"(r) : "v"(lo), "v"(hi));
  return r;
}
__device__ __forceinline__ f32x4 mfma16(bf16x8 a, bf16x8 b, f32x4 c) {
  return __builtin_amdgcn_mfma_f32_16x16x32_bf16(a, b, c, 0, 0, 0);
}

union U16x8 { u16 u[8]; uint4 q; };

// ---------------- prep: weights -> fragment-ordered bf16, collapsed head ----
__global__ void lstm_prep_w(const float* Wih0, const float* Whh0,
                            const float* bih0, const float* bhh0,
                            const float* Wih1, const float* Whh1,
                            const float* bih1, const float* bhh1,
                            const float* muW1, const float* mub1,
                            const float* muW2, const float* mub2,
                            const float* sgW1, const float* sgb1,
                            const float* sgW2, const float* sgb2,
                            unsigned char* ws)
{
  int id = blockIdx.x * 256 + threadIdx.x;
  u16* whh0_f = (u16*)(ws + OFF_WHH0);
  u16* wih0_f = (u16*)(ws + OFF_WIH0);
  u16* w1_f   = (u16*)(ws + OFF_W1);
  float* b0   = (float*)(ws + OFF_B0);
  float* b1   = (float*)(ws + OFF_B1);
  float* weff = (float*)(ws + OFF_WEFF);
  float* beff = (float*)(ws + OFF_BEFF);

  if (id < 8192) {                       // Whh0 frags: [w][g][kf][lane][8]
    int fid = id >> 6, lane = id & 63;
    int w = fid >> 4, g = (fid >> 2) & 3, kf = fid & 3;
    int r = g*128 + w*16 + (lane & 15);
    int k = kf*32 + (lane >> 4)*8;
    const float* src = Whh0 + r*128 + k;
    U16x8 t;
    #pragma unroll
    for (int i = 0; i < 8; ++i) t.u[i] = f2bu(src[i]);
    ((uint4*)whh0_f)[id] = t.q;
  } else if (id < 10240) {               // Wih0 frags (K=8 in 32, zero-padded)
    int c = id - 8192; int fid = c >> 6, lane = c & 63;
    int w = fid >> 2, g = fid & 3;
    U16x8 t;
    #pragma unroll
    for (int i = 0; i < 8; ++i) t.u[i] = 0;
    if (lane < 16) {
      int r = g*128 + w*16 + lane;
      #pragma unroll
      for (int i = 0; i < 8; ++i) t.u[i] = f2bu(Wih0[r*8 + i]);
    }
    ((uint4*)wih0_f)[c] = t.q;
  } else if (id < 26624) {               // W1 = [Wih1 ; Whh1] frags, K=256
    int c = id - 10240; int fid = c >> 6, lane = c & 63;
    int w = fid >> 5, g = (fid >> 3) & 3, kf = fid & 7;
    int r = g*128 + w*16 + (lane & 15);
    int k = kf*32 + (lane >> 4)*8;
    const float* src = (k < 128) ? (Wih1 + r*128 + k) : (Whh1 + r*128 + (k-128));
    U16x8 t;
    #pragma unroll
    for (int i = 0; i < 8; ++i) t.u[i] = f2bu(src[i]);
    ((uint4*)w1_f)[c] = t.q;
  } else if (id < 27136) {               // b0 arranged
    int i = id - 26624; int w = i >> 6, g = (i >> 4) & 3, cc = i & 15;
    int r = g*128 + w*16 + cc;
    b0[i] = bih0[r] + bhh0[r];
  } else if (id < 27648) {               // b1 arranged
    int i = id - 27136; int w = i >> 6, g = (i >> 4) & 3, cc = i & 15;
    int r = g*128 + w*16 + cc;
    b1[i] = bih1[r] + bhh1[r];
  } else if (id < 28160) {               // collapsed head W: [4][128]
    int i = id - 27648; int o = i >> 7, k = i & 127;
    const float* W1p = (o < 2) ? muW1 : sgW1;
    const float* W2p = (o < 2) ? muW2 : sgW2;
    int oo = o & 1;
    float s = 0.f;
    for (int m = 0; m < 64; ++m) s += W2p[oo*64 + m] * W1p[m*128 + k];
    weff[i] = s;
  } else if (id < 28164) {               // collapsed head bias [4]
    int o = id - 28160; int oo = o & 1;
    const float* W2p = (o < 2) ? muW2 : sgW2;
    const float* b1p = (o < 2) ? mub1 : sgb1;
    const float* b2p = (o < 2) ? mub2 : sgb2;
    float s = b2p[oo];
    for (int m = 0; m < 64; ++m) s += W2p[oo*64 + m] * b1p[m];
    beff[o] = s;
  }
}

// ---------------- prep: in_tensor [B,T,N,D] fp32 -> xb [T, BN, 8] bf16 ------
__global__ void lstm_prep_x(const float* in, unsigned char* ws)
{
  int id = blockIdx.x * 256 + threadIdx.x;     // < 524288
  if (id >= T_STEPS * BN_TOT) return;
  int t = id >> 13, s = id & 8191, b = s >> 9, n = s & 511;
  const float* src = in + (((b*64) + t)*512 + n)*8;
  U16x8 v;
  #pragma unroll
  for (int i = 0; i < 8; ++i) v.u[i] = f2bu(src[i]);
  *(uint4*)(ws + OFF_XB + (size_t)id * 16) = v.q;
}

// ---------------- main: fused 2-layer LSTM + head ---------------------------
// R13 = R12 (best: 234us, zero-spill) + register-neutral VALU cuts:
// 1) zero-C MFMA init (inline-constant C) -- deletes 64 v_mov splats/step.
//    Bias enters via ACT: e = exp2(fma(acc, k, k*b)) (mul -> fma, free).
// 2) fmed3 clamp for c saturation.
// Schedule (R12): body(t) = [L1m(t); ACT1(t)->bufB; x(t+1); L0m(t+1);
//                            ACT0(t+1)->bufA'; BAR]   -- 1 barrier/step.
// ACT algebra (exact): a_i = 1+exp(-gate'), gate' = acc+b (bias in exp arg)
//   c = [c_prev*a1*a3 + (1-eg)*a2] * rcp(a1*a2*a3)
//   h = (1-ec) * rcp((1+eo)*(1+ec)),  ec = exp(-2*med3(c,-40,40))
// h layout: col-block-major, addr(row,col) = (col>>3)*512 + row*16 + (col&7)*2
#define ACT_BLOCK(ACC, CS, NB, HBASE)                                      \
  { _Pragma("unroll")                                                      \
    for (int mf = 0; mf < 2; ++mf) {                                       \
      float hq[4];                                                         \
      _Pragma("unroll")                                                    \
      for (int q = 0; q < 4; ++q) {                                        \
        float ei = __builtin_amdgcn_exp2f(fmaf(ACC[mf][0][q], -1.44269504f, NB[0])); \
        float ef = __builtin_amdgcn_exp2f(fmaf(ACC[mf][1][q], -1.44269504f, NB[1])); \
        float eg = __builtin_amdgcn_exp2f(fmaf(ACC[mf][2][q], -2.88539008f, NB[2])); \
        float eo = __builtin_amdgcn_exp2f(fmaf(ACC[mf][3][q], -1.44269504f, NB[3])); \
        float a1 = 1.0f + ei, a2 = 1.0f + ef, a3 = 1.0f + eg;              \
        float p13 = a1 * a3;                                               \
        float num = fmaf(CS[mf][q], p13, (1.0f - eg) * a2);                \
        float c = num * __builtin_amdgcn_rcpf(p13 * a2);                   \
        CS[mf][q] = c;                                                     \
        float cc = __builtin_amdgcn_fmed3f(c, -40.0f, 40.0f);              \
        float ec = __builtin_amdgcn_exp2f(-2.88539008f * cc);              \
        hq[q] = (1.0f - ec) * __builtin_amdgcn_rcpf((1.0f + eo) * (1.0f + ec)); \
      }                                                                    \
      unsigned p01 = cvt_pk_bf16(hq[0], hq[1]);                            \
      unsigned p23 = cvt_pk_bf16(hq[2], hq[3]);                            \
      int rb = (mf*16 + lk*4);                                             \
      *(u16*)((HBASE) + wb + (rb  )*16) = (u16)p01;                        \
      *(u16*)((HBASE) + wb + (rb+1)*16) = (u16)(p01 >> 16);                \
      *(u16*)((HBASE) + wb + (rb+2)*16) = (u16)p23;                        \
      *(u16*)((HBASE) + wb + (rb+3)*16) = (u16)(p23 >> 16);                \
    } }

__global__ __launch_bounds__(512, 2) void lstm_fused(const unsigned char* ws, float* out)
{
  extern __shared__ unsigned char lds[];
  u16* whh0_lds = (u16*)lds;                 // [w][g][kf][lane][8] frags, 128KB
  unsigned char* hA0 = lds + 131072;
  unsigned char* hA1 = hA0 + HB;
  unsigned char* hB0 = hA1 + HB;
  unsigned char* hB1 = hB0 + HB;

  const u16* whh0_f = (const u16*)(ws + OFF_WHH0);
  const u16* wih0_f = (const u16*)(ws + OFF_WIH0);
  const u16* w1_f   = (const u16*)(ws + OFF_W1);
  const float* b0a  = (const float*)(ws + OFF_B0);
  const float* b1a  = (const float*)(ws + OFF_B1);
  const float* weff = (const float*)(ws + OFF_WEFF);
  const float* beff = (const float*)(ws + OFF_BEFF);
  const u16* xb     = (const u16*)(ws + OFF_XB);

  const int tid = threadIdx.x;
  const int w = tid >> 6, l = tid & 63;
  const int lrow = l & 15, lk = l >> 4;
  const int s0 = blockIdx.x * BM;
  const int wb = (w*2 + (lrow >> 3))*512 + (lrow & 7)*2;   // ACT write base

  // stage Whh0 frags into LDS (straight 16B copies, layout identical)
  for (int i = tid; i < 8192; i += 512)
    ((uint4*)whh0_lds)[i] = ((const uint4*)whh0_f)[i];
  // zero all four h buffers (contiguous 32KB)
  for (int i = tid; i < 8192; i += 512) ((u32*)hA0)[i] = 0;

  // persistent register weights (plain arrays, builtin consumers: compiler
  // promotes w1r to AGPRs itself -- R2/R9/R12 evidence)
  bf16x8 w1r[4][8];
  #pragma unroll
  for (int g = 0; g < 4; ++g)
    #pragma unroll
    for (int kf = 0; kf < 8; ++kf)
      w1r[g][kf] = *(const bf16x8*)(w1_f + ((((w*4+g)*8)+kf)*64 + l)*8);
  bf16x8 wih0r[4];
  #pragma unroll
  for (int g = 0; g < 4; ++g)
    wih0r[g] = *(const bf16x8*)(wih0_f + ((w*4+g)*64 + l)*8);
  // pre-scaled biases: nb[g] = k_g * b[g], k = -1.4427 (sig) / -2.8854 (tanh)
  float nb0[4], nb1[4];
  #pragma unroll
  for (int g = 0; g < 4; ++g) {
    float kg = (g == 2) ? -2.88539008f : -1.44269504f;
    nb0[g] = kg * b0a[w*64 + g*16 + lrow];
    nb1[g] = kg * b1a[w*64 + g*16 + lrow];
  }
  float c_a[2][4] = {{0,0,0,0},{0,0,0,0}};
  float c_b[2][4] = {{0,0,0,0},{0,0,0,0}};
  const f32x4 zc = {0.0f, 0.0f, 0.0f, 0.0f};

  // pointer roles at loop iter t: aR = bufA[t&1] (read by L1m(t), L0m(t+1)),
  // aW = bufA[1-(t&1)] (ACT0(t+1) dst), bR = bufB[1-(t&1)], bW = bufB[t&1].
  unsigned char *aR = hA0, *aW = hA1, *bR = hB1, *bW = hB0;

  __syncthreads();

  // ---- peel: L0m(0) on hA(-1)=bufA[1]=0, ACT0(0)->bufA[0] ------------------
  {
    const u16* xrow = xb + (size_t)(s0 + lrow)*8;
    bf16x8 xf0 = *(const bf16x8*)xrow;          // lanes lk>0: B rows >=8 are 0
    bf16x8 xf1 = *(const bf16x8*)(xrow + 128);
    f32x4 acc0[2][4];
    #pragma unroll
    for (int g = 0; g < 4; ++g) {
      acc0[0][g] = mfma16(xf0, wih0r[g], zc);
      acc0[1][g] = mfma16(xf1, wih0r[g], zc);
    }
    // hA(-1) is zero: skip the 32 hh-MFMAs
    ACT_BLOCK(acc0, c_a, nb0, aR);              // hA(0) -> bufA[0]
  }
  __syncthreads();                              // BAR(-1->0): hA(0) visible

  // ---- main loop t = 0..62: one barrier per step ---------------------------
  #pragma unroll 1
  for (int t = 0; t < T_STEPS - 1; ++t) {
    // L1m(t): hA(t)@Wih1 + hB(t-1)@Whh1  (W1 in AGPRs; C=0 on first kf)
    f32x4 acc1[2][4];
    {
      bf16x8 a0 = *(const bf16x8*)(aR + lk*512 + lrow*16);
      bf16x8 a1 = *(const bf16x8*)(aR + lk*512 + (16 + lrow)*16);
      #pragma unroll
      for (int g = 0; g < 4; ++g) {
        acc1[0][g] = mfma16(a0, w1r[g][0], zc);
        acc1[1][g] = mfma16(a1, w1r[g][0], zc);
      }
    }
    #pragma unroll
    for (int kf = 1; kf < 8; ++kf) {
      const unsigned char* hs = (kf < 4) ? aR : bR;
      bf16x8 a0 = *(const bf16x8*)(hs + ((kf & 3)*4 + lk)*512 + lrow*16);
      bf16x8 a1 = *(const bf16x8*)(hs + ((kf & 3)*4 + lk)*512 + (16 + lrow)*16);
      #pragma unroll
      for (int g = 0; g < 4; ++g) {
        acc1[0][g] = mfma16(a0, w1r[g][kf], acc1[0][g]);
        acc1[1][g] = mfma16(a1, w1r[g][kf], acc1[1][g]);
      }
    }
    ACT_BLOCK(acc1, c_b, nb1, bW);              // hB(t) -> bufB[t&1]

    // x(t+1) (L2-resident; latency hidden under surrounding MFMAs)
    const u16* xrow = xb + (size_t)((t+1)*8192 + s0 + lrow)*8;
    bf16x8 xf0 = *(const bf16x8*)xrow;
    bf16x8 xf1 = *(const bf16x8*)(xrow + 128);

    // L0m(t+1): x(t+1)@Wih0 + hA(t)@Whh0 -- independent of ACT1(t),
    // same basic block -> scheduler may overlap ACT1 VALU with these MFMAs.
    f32x4 acc0[2][4];
    #pragma unroll
    for (int g = 0; g < 4; ++g) {
      acc0[0][g] = mfma16(xf0, wih0r[g], zc);
      acc0[1][g] = mfma16(xf1, wih0r[g], zc);
    }
    #pragma unroll
    for (int kf = 0; kf < 4; ++kf) {
      bf16x8 a0 = *(const bf16x8*)(aR + (kf*4 + lk)*512 + lrow*16);
      bf16x8 a1 = *(const bf16x8*)(aR + (kf*4 + lk)*512 + (16 + lrow)*16);
      #pragma unroll
      for (int g = 0; g < 4; ++g) {
        bf16x8 bfr = *(const bf16x8*)(whh0_lds + ((w*16 + g*4 + kf)*64 + l)*8);
        acc0[0][g] = mfma16(a0, bfr, acc0[0][g]);
        acc0[1][g] = mfma16(a1, bfr, acc0[1][g]);
      }
    }
    ACT_BLOCK(acc0, c_a, nb0, aW);              // hA(t+1) -> bufA[(t+1)&1]

    __syncthreads();                            // the ONE barrier per step
    { unsigned char* tp = aR; aR = aW; aW = tp; }
    { unsigned char* tp = bR; bR = bW; bW = tp; }
  }

  // ---- epilogue: L1m(63) + ACT1(63) -> bW = bufB[1] ------------------------
  {
    f32x4 acc1[2][4];
    {
      bf16x8 a0 = *(const bf16x8*)(aR + lk*512 + lrow*16);
      bf16x8 a1 = *(const bf16x8*)(aR + lk*512 + (16 + lrow)*16);
      #pragma unroll
      for (int g = 0; g < 4; ++g) {
        acc1[0][g] = mfma16(a0, w1r[g][0], zc);
        acc1[1][g] = mfma16(a1, w1r[g][0], zc);
      }
    }
    #pragma unroll
    for (int kf = 1; kf < 8; ++kf) {
      const unsigned char* hs = (kf < 4) ? aR : bR;
      bf16x8 a0 = *(const bf16x8*)(hs + ((kf & 3)*4 + lk)*512 + lrow*16);
      bf16x8 a1 = *(const bf16x8*)(hs + ((kf & 3)*4 + lk)*512 + (16 + lrow)*16);
      #pragma unroll
      for (int g = 0; g < 4; ++g) {
        acc1[0][g] = mfma16(a0, w1r[g][kf], acc1[0][g]);
        acc1[1][g] = mfma16(a1, w1r[g][kf], acc1[1][g]);
      }
    }
    ACT_BLOCK(acc1, c_b, nb1, bW);
  }
  __syncthreads();                              // final hB visible for head

  // ---- head: out = sigmoid(h_final @ Weff^T + beff), sigma *= 0.5 ----------
  if (tid < BM*4) {
    int m = tid >> 2, o = tid & 3;
    const float* wr = weff + o*128;
    float d = beff[o];
    #pragma unroll 4
    for (int kk = 0; kk < 16; ++kk) {
      bf16x8 hv = *(const bf16x8*)(bW + kk*512 + m*16);
      #pragma unroll
      for (int j = 0; j < 8; ++j) d += bu2f((u16)hv[j]) * wr[kk*8 + j];
    }
    float v = fsig(d);
    if (o >= 2) v *= 0.5f;
    int s = s0 + m;
    out[(o >= 2 ? 16384 : 0) + s*2 + (o & 1)] = v;
  }
}

extern "C" void kernel_launch(void* const* d_in, const int* in_sizes, int n_in,
                              void* d_out, int out_size, void* d_ws, size_t ws_size,
                              hipStream_t stream) {
  (void)in_sizes; (void)n_in; (void)out_size; (void)ws_size;
  const float* in_tensor = (const float*)d_in[0];
  const float* Wih0 = (const float*)d_in[1];
  const float* Whh0 = (const float*)d_in[2];
  const float* bih0 = (const float*)d_in[3];
  const float* bhh0 = (const float*)d_in[4];
  const float* Wih1 = (const float*)d_in[5];
  const float* Whh1 = (const float*)d_in[6];
  const float* bih1 = (const float*)d_in[7];
  const float* bhh1 = (const float*)d_in[8];
  const float* muW1 = (const float*)d_in[9];
  const float* mub1 = (const float*)d_in[10];
  const float* muW2 = (const float*)d_in[11];
  const float* mub2 = (const float*)d_in[12];
  const float* sgW1 = (const float*)d_in[13];
  const float* sgb1 = (const float*)d_in[14];
  const float* sgW2 = (const float*)d_in[15];
  const float* sgb2 = (const float*)d_in[16];
  unsigned char* ws = (unsigned char*)d_ws;
  float* out = (float*)d_out;

  lstm_prep_w<<<dim3(111), dim3(256), 0, stream>>>(
      Wih0, Whh0, bih0, bhh0, Wih1, Whh1, bih1, bhh1,
      muW1, mub1, muW2, mub2, sgW1, sgb1, sgW2, sgb2, ws);
  lstm_prep_x<<<dim3(2048), dim3(256), 0, stream>>>(in_tensor, ws);

  (void)hipFuncSetAttribute((const void*)lstm_fused,
                            hipFuncAttributeMaxDynamicSharedMemorySize, LDS_BYTES);
  lstm_fused<<<dim3(256), dim3(512), LDS_BYTES, stream>>>(ws, out);
}